// Round 6
// baseline (103.834 us; speedup 1.0000x reference)
//
#include <hip/hip_runtime.h>
#include <math.h>

constexpr int kH = 64, kW = 128, kB = 2, kS = 4;
constexpr int kNP = kH * kW;          // 8192 points per set
constexpr int kPairs = kB * kS;       // 8
constexpr int kDirs = kPairs * 2;     // 16
constexpr float kPen = 32768.0f;      // exclusion penalty (bf16-exact pow2)
constexpr float kPi = 3.14159265358979323846f;
constexpr float kFovUp = 3.0f * kPi / 180.0f;
constexpr float kFovDown = -25.0f * kPi / 180.0f;

typedef short short8 __attribute__((ext_vector_type(8)));
typedef unsigned short ushort8 __attribute__((ext_vector_type(8)));
typedef float floatx16 __attribute__((ext_vector_type(16)));

// R17: R16 post-mortem — doubling waves/SIMD changed nothing (47.2->47.5us):
// the wall is not latency/TLP but a saturated shared resource. Cross-round
// arithmetic fingers the 1M device-scope atomicMins (~21/ns = plausible
// fabric-atomic saturation; R12's 2M atomics = 2x the wall at 89.7us; R11's
// heavier compute covered the same stream at 88% busy-sum).
// Fix: NO global atomicMin. Each block plain-stores (agent-scope, coherent)
// its per-chunk partial mins to minpart[d][ch][q]; a 3-stage deterministic
// ticket reduction folds them: (1) last block of each (d,qb) group folds 8
// chunk partials for its 1024 queries, (2) last group of each dir sums the 8
// (wsum,msum) pairs in fixed order, (3) final block combines 16 dirs.
// Main loop / tile constants byte-identical to R16 (proven VGPR-40 codegen;
// R15 lesson: don't perturb the constant set).
constexpr int NCC = 8;                // candidate chunks
constexpr int CCH = kNP / NCC;        // 1024 candidates per chunk
constexpr int NQB = 8;                // query blocks (8192/1024)
constexpr int QT = 4;                 // 32-query tiles per wave (128 q/wave)
constexpr int BT = 512;               // threads per block (8 waves)
// grid = 16 dirs * 8 * 8 = 1024 blocks = exactly 4 per CU (one clean round)

// ws layout (float offsets)
// pts    : [kDirs][kNP] float4 -> 524288 floats @ 0          (2 MB)
// minpart: [kDirs][NCC][kNP] u32 -> 1048576   @ 524288       (4 MB)
// qpart  : [kDirs][NQB][2] f32 -> 256         @ 1572864
// gcnt   : [kDirs*NQB] u32     -> 128         @ 1573120
// dcnt   : [kDirs] u32         -> 16          @ 1573248
// mval   : [kDirs] f32         -> 16          @ 1573264
// acnt   : u32                 -> 1           @ 1573280
constexpr size_t OFF_MINPART = 524288;
constexpr size_t OFF_QPART = 1572864;
constexpr size_t OFF_GCNT = 1573120;
constexpr size_t OFF_DCNT = 1573248;
constexpr size_t OFF_MVAL = 1573264;
constexpr size_t OFF_ACNT = 1573280;

__device__ __forceinline__ unsigned short f2bf(float v) {
  unsigned u = __float_as_uint(v);
  unsigned r = u + 0x7FFFu + ((u >> 16) & 1u);   // RNE
  return (unsigned short)(r >> 16);
}
__device__ __forceinline__ float bf2f(unsigned short b) {
  return __uint_as_float(((unsigned)b) << 16);
}

// Candidate record F (16 bf16 K-slots, K=16 MFMA) with query record G:
//  k : 0    1    2    3    4    5    6    7  | 8    9    10   11   12-15
//  F : Xh   Xl   Xh   Yh   Yl   Yh   Zh   Zl | Zh   Ch   Cl   Cl2  0
//  G : xh   xh   xl   yh   yh   yl   zh   zh | zl   1    1    1    0
// sum_k F*G = X*x + Y*y + Z*z + ct  (drops only lo*lo terms ~2e-4)

__global__ __launch_bounds__(256) void prep_kernel(
    const float* __restrict__ rv, const float* __restrict__ tgt,
    float4* __restrict__ pts, unsigned* __restrict__ gcnt,
    float* __restrict__ mval, unsigned* __restrict__ dcnt,
    unsigned* __restrict__ acnt) {
  int idx = blockIdx.x * 256 + threadIdx.x;   // [0, kPairs*kNP)
  int p = idx >> 13;
  int k = idx & (kNP - 1);
  int h = k >> 7;
  int w = k & 127;

  float r = rv[idx];
  float pitch = (1.0f - (h + 0.5f) * (1.0f / kH)) * (kFovUp - kFovDown) + kFovDown;
  float yaw = -(((w + 0.5f) * (1.0f / kW)) * 2.0f - 1.0f) * kPi;
  float cp = __cosf(pitch), sp = __sinf(pitch);
  float cy = __cosf(yaw), sy = __sinf(yaw);
  float px = r * cp * cy, py = r * cp * sy, pz = r * sp;
  float mo = (r > 0.0f) ? 1.0f : 0.0f;

  const float* tb = tgt + (size_t)p * 4 * kNP;
  float mt = (tb[k] > 0.0f) ? 1.0f : 0.0f;
  float tx = tb[kNP + k], ty = tb[2 * kNP + k], tz = tb[3 * kNP + k];

  float no = px * px + py * py + pz * pz;
  float nt = tx * tx + ty * ty + tz * tz;
  float co = no + kPen * (1.0f - mo);
  float ct = nt + kPen * (1.0f - mt);

  int d0 = 2 * p, d1 = d0 + 1;
  // pts.w < 16384 <=> valid point; equals |p|^2 then. Candidates of dir d
  // are exactly pts[d^1] (dir0 candidates = tgt pts = dir1 queries).
  pts[(size_t)d0 * kNP + k] = make_float4(px, py, pz, co);
  pts[(size_t)d1 * kNP + k] = make_float4(tx, ty, tz, ct);

  if (idx < kDirs * NQB) gcnt[idx] = 0u;
  if (idx < kDirs) { dcnt[idx] = 0u; mval[idx] = 0.0f; }
  if (idx == kDirs) *acnt = 0u;
  // minpart needs no init: every (d,ch,q) slot is written each launch.
}

__global__ __launch_bounds__(BT) void nn_kernel(
    const float4* __restrict__ pts, unsigned* __restrict__ minpart,
    float* __restrict__ qpart, unsigned* __restrict__ gcnt,
    float* __restrict__ mval, unsigned* __restrict__ dcnt,
    unsigned* __restrict__ acnt, float* __restrict__ out) {
  // 32 KB candidate records: 32 ctiles of 1 KB = [32 rows x 8 lo][32 rows x 8 hi]
  // laid out so lane l's A-fragment is at byte offset l*16 (linear ds_read_b128).
  // +1 KB slack so the loop's A-prefetch may harmlessly overread one tile.
  __shared__ __align__(16) unsigned short sc[CCH * 16 + 512];
  __shared__ unsigned s_ticket;
  __shared__ float sw[8], sm[8];

  int bid = blockIdx.x;
  int d = bid >> 6;            // 64 blocks per dir
  int qb = (bid >> 3) & 7;
  int ch = bid & 7;
  int t = threadIdx.x;

  // ---- build candidate records in LDS directly from pts[d^1] ----
  const float4* cand = pts + (size_t)(d ^ 1) * kNP + ch * CCH;
#pragma unroll
  for (int i = 0; i < 2; ++i) {
    int j = t + i * BT;
    float4 P = cand[j];
    float X = -2.0f * P.x, Y = -2.0f * P.y, Z = -2.0f * P.z;
    float ct = P.w;
    unsigned short Xh = f2bf(X), Yh = f2bf(Y), Zh = f2bf(Z);
    unsigned short Xl = f2bf(X - bf2f(Xh));
    unsigned short Yl = f2bf(Y - bf2f(Yh));
    unsigned short Zl = f2bf(Z - bf2f(Zh));
    unsigned short Ch = f2bf(ct);
    float c1 = ct - bf2f(Ch);
    unsigned short Cl = f2bf(c1);
    unsigned short Cl2 = f2bf(c1 - bf2f(Cl));
    // ctile (j>>5): lo-half (k0..7) at slot (j&31), hi-half (k8..15) at +32
    unsigned short* dst = sc + (j >> 5) * 512 + (j & 31) * 8;
    *(ushort8*)dst = (ushort8){Xh, Xl, Xh, Yh, Yl, Yh, Zh, Zl};
    *(ushort8*)(dst + 256) = (ushort8){Zh, Ch, Cl, Cl2, 0, 0, 0, 0};
  }
  __syncthreads();

  int wave = t >> 6, lane = t & 63;
  int col = lane & 31, half = lane >> 5;   // B: col = lane&31 (HW-verified)
  int qbase = d * kNP + qb * 1024 + wave * 128;

  const short one_bf = (short)0x3F80;  // bf16(1.0)
  short8 bq[QT];
  float mn[QT];
#pragma unroll
  for (int qt = 0; qt < QT; ++qt) {
    float4 P = pts[qbase + qt * 32 + col];
    unsigned short xh = f2bf(P.x), yh = f2bf(P.y), zh = f2bf(P.z);
    unsigned short xl = f2bf(P.x - bf2f(xh));
    unsigned short yl = f2bf(P.y - bf2f(yh));
    unsigned short zl = f2bf(P.z - bf2f(zh));
    short8 b;
    if (half == 0)
      b = (short8){(short)xh, (short)xh, (short)xl, (short)yh,
                   (short)yh, (short)yl, (short)zh, (short)zh};
    else
      b = (short8){(short)zl, one_bf, one_bf, one_bf, 0, 0, 0, 0};
    bq[qt] = b;
    mn[qt] = 3.0e38f;
  }

  floatx16 zc = {0.0f, 0.0f, 0.0f, 0.0f, 0.0f, 0.0f, 0.0f, 0.0f,
                 0.0f, 0.0f, 0.0f, 0.0f, 0.0f, 0.0f, 0.0f, 0.0f};

  // A fragment: lane l holds row l&31, K-half l>>5 -> linear offset l*16 B.
  const short8* ap = (const short8*)sc + lane;   // stride 64 short8s per ctile
  short8 a = ap[0];
#pragma unroll 2
  for (int ctile = 0; ctile < CCH / 32; ++ctile) {
    short8 an = ap[(ctile + 1) * 64];   // prefetch next tile (slack covers last)
#pragma unroll
    for (int qt = 0; qt < QT; ++qt) {
      floatx16 dr =
          __builtin_amdgcn_mfma_f32_32x32x16_bf16(a, bq[qt], zc, 0, 0, 0);
      // 16->1 row-min fold, min3-shaped (compiler emits ~8 v_min3)
      float f0 = fminf(fminf(dr[0], dr[1]), dr[2]);
      float f1 = fminf(fminf(dr[3], dr[4]), dr[5]);
      float f2 = fminf(fminf(dr[6], dr[7]), dr[8]);
      float f3 = fminf(fminf(dr[9], dr[10]), dr[11]);
      float f4 = fminf(fminf(dr[12], dr[13]), dr[14]);
      float g0 = fminf(fminf(f0, f1), dr[15]);
      float g1 = fminf(fminf(f2, f3), f4);
      mn[qt] = fminf(fminf(g0, g1), mn[qt]);
    }
    a = an;
  }

  // ---- publish per-chunk partial mins: PLAIN agent-scope stores (coherent
  // at the device point, full-BW, no RMW serialization — the R16 wall) ----
#pragma unroll
  for (int qt = 0; qt < QT; ++qt) {
    float m = fminf(mn[qt], __shfl_xor(mn[qt], 32));
    if (lane < 32)
      __hip_atomic_store(
          &minpart[(size_t)(d * NCC + ch) * kNP + qb * 1024 + wave * 128 +
                   qt * 32 + lane],
          __float_as_uint(m), __ATOMIC_RELAXED, __HIP_MEMORY_SCOPE_AGENT);
  }

  // ---- stage 1: last block of this (d,qb) group folds the 8 chunk partials
  // NO __threadfence (R8/R10/R11: device fences emit buffer_wbl2/inv that
  // serialize device-wide). __syncthreads' implicit s_waitcnt vmcnt(0) drains
  // our agent stores before the ticket increment; ticket==7 therefore implies
  // all 8 blocks' stores are visible at the coherent point.
  __syncthreads();
  if (t == 0)
    s_ticket = __hip_atomic_fetch_add(&gcnt[d * NQB + qb], 1u, __ATOMIC_RELAXED,
                                      __HIP_MEMORY_SCOPE_AGENT);
  __syncthreads();
  if (s_ticket != (unsigned)(NCC - 1)) return;

  float wsum = 0.0f, msum = 0.0f;
#pragma unroll
  for (int r = 0; r < 1024 / BT; ++r) {     // 2 iterations
    int q = qb * 1024 + r * BT + t;         // dir-local query index
    float mv = 3.0e38f;
#pragma unroll
    for (int c = 0; c < NCC; ++c) {
      unsigned u = __hip_atomic_load(&minpart[(size_t)(d * NCC + c) * kNP + q],
                                     __ATOMIC_RELAXED, __HIP_MEMORY_SCOPE_AGENT);
      mv = fminf(mv, __uint_as_float(u));
    }
    float4 P = pts[(size_t)d * kNP + q];
    if (P.w < 16384.0f) {
      wsum += P.w + mv;
      msum += 1.0f;
    }
  }
#pragma unroll
  for (int off = 32; off; off >>= 1) {
    wsum += __shfl_down(wsum, off);
    msum += __shfl_down(msum, off);
  }
  if ((t & 63) == 0) { sw[t >> 6] = wsum; sm[t >> 6] = msum; }
  __syncthreads();
  if (t == 0) {
    float ws_ = 0.0f, ms_ = 0.0f;
#pragma unroll
    for (int w2 = 0; w2 < 8; ++w2) { ws_ += sw[w2]; ms_ += sm[w2]; }
    int g = d * NQB + qb;
    __hip_atomic_store(&qpart[g * 2], ws_, __ATOMIC_RELAXED,
                       __HIP_MEMORY_SCOPE_AGENT);
    __hip_atomic_store(&qpart[g * 2 + 1], ms_, __ATOMIC_RELAXED,
                       __HIP_MEMORY_SCOPE_AGENT);
    // RELEASE orders the qpart stores before this RMW (waitcnt, no L2 flush
    // — the proven mval/acnt pattern). 128 of these per launch.
    s_ticket = __hip_atomic_fetch_add(&dcnt[d], 1u, __ATOMIC_ACQ_REL,
                                      __HIP_MEMORY_SCOPE_AGENT);
  }
  __syncthreads();
  if (s_ticket != (unsigned)(NQB - 1)) return;

  // ---- stage 2: last group of this dir sums the 8 partial pairs (fixed
  // order -> deterministic) ----
  if (t == 0) {
    float W = 0.0f, M = 0.0f;
#pragma unroll
    for (int g = 0; g < NQB; ++g) {
      W += __uint_as_float(__hip_atomic_load(
          (unsigned*)&qpart[(d * NQB + g) * 2], __ATOMIC_RELAXED,
          __HIP_MEMORY_SCOPE_AGENT));
      M += __uint_as_float(__hip_atomic_load(
          (unsigned*)&qpart[(d * NQB + g) * 2 + 1], __ATOMIC_RELAXED,
          __HIP_MEMORY_SCOPE_AGENT));
    }
    __hip_atomic_store(&mval[d], W / fmaxf(M, 1.0f), __ATOMIC_RELAXED,
                       __HIP_MEMORY_SCOPE_AGENT);
    s_ticket = __hip_atomic_fetch_add(acnt, 1u, __ATOMIC_ACQ_REL,
                                      __HIP_MEMORY_SCOPE_AGENT);
  }
  __syncthreads();
  if (s_ticket != (unsigned)(kDirs - 1)) return;
  // ---- stage 3: very last block combines 16 dir values into 12 outputs ----
  if (t == 0) {
    float mv[kDirs];
    for (int dd = 0; dd < kDirs; ++dd)
      mv[dd] = __hip_atomic_load(&mval[dd], __ATOMIC_RELAXED,
                                 __HIP_MEMORY_SCOPE_AGENT);
    for (int s = 0; s < kS; ++s) {
      float acc = 0.0f;
      for (int b = 0; b < kB; ++b) {
        int p = b * kS + s;
        float tens = mv[2 * p] + mv[2 * p + 1];
        out[kS + s * kB + b] = tens;
        acc += tens;
      }
      out[s] = acc * (1.0f / kB);
    }
  }
}

extern "C" void kernel_launch(void* const* d_in, const int* in_sizes, int n_in,
                              void* d_out, int out_size, void* d_ws, size_t ws_size,
                              hipStream_t stream) {
  const float* rv = (const float*)d_in[0];
  const float* tgt = (const float*)d_in[1];
  float* ws = (float*)d_ws;
  float4* pts = (float4*)ws;
  unsigned* minpart = (unsigned*)(ws + OFF_MINPART);
  float* qpart = ws + OFF_QPART;
  unsigned* gcnt = (unsigned*)(ws + OFF_GCNT);
  unsigned* dcnt = (unsigned*)(ws + OFF_DCNT);
  float* mval = ws + OFF_MVAL;
  unsigned* acnt = (unsigned*)(ws + OFF_ACNT);
  float* out = (float*)d_out;

  hipLaunchKernelGGL(prep_kernel, dim3(kPairs * kNP / 256), dim3(256), 0, stream,
                     rv, tgt, pts, gcnt, mval, dcnt, acnt);
  hipLaunchKernelGGL(nn_kernel, dim3(kDirs * NQB * NCC), dim3(BT), 0, stream,
                     pts, minpart, qpart, gcnt, mval, dcnt, acnt, out);
}

// Round 7
// 97.849 us; speedup vs baseline: 1.0612x; 1.0612x over previous
//
#include <hip/hip_runtime.h>
#include <math.h>

constexpr int kH = 64, kW = 128, kB = 2, kS = 4;
constexpr int kNP = kH * kW;          // 8192 points per set
constexpr int kPairs = kB * kS;       // 8
constexpr int kDirs = kPairs * 2;     // 16
constexpr float kPen = 32768.0f;      // exclusion penalty (bf16-exact pow2)
constexpr float kPi = 3.14159265358979323846f;
constexpr float kFovUp = 3.0f * kPi / 180.0f;
constexpr float kFovDown = -25.0f * kPi / 180.0f;

typedef short short8 __attribute__((ext_vector_type(8)));
typedef unsigned short ushort8 __attribute__((ext_vector_type(8)));
typedef float floatx16 __attribute__((ext_vector_type(16)));

// R18: R17 post-mortem — removing ALL 1M atomicMins made it SLOWER (47.5 ->
// 53.7): atomics were never the wall. R16 already showed 2x waves/SIMD = no
// change. Every pipe-level theory is dead; bottom-up pipe demand is ~15 us
// yet the kernel sits at ~47-54 invariantly. Last unpriced structure: the
// in-kernel ticket/tail (every block runs syncthreads+ticket; winner gathers
// on a draining GPU behind the slowest straggler; R17's extra stages cost
// +6.2 us for ~2 us of nominal work).
// Fix + bisect in one: nn_kernel = PURE main loop ending in plain float
// stores of per-chunk partial mins (no sync, no tickets, no atomics, no
// encode). A separate reduce_kernel (128 blocks) folds minpart via plain
// coalesced loads (cross-kernel producer->consumer ordering is the supported
// pattern) and runs the tiny qpart->mval->out ticket chain (17 RMWs).
// Main-loop constants byte-identical to the proven VGPR-40 codegen.
constexpr int NCC = 8;                // candidate chunks
constexpr int CCH = kNP / NCC;        // 1024 candidates per chunk
constexpr int NQB = 8;                // query blocks (8192/1024)
constexpr int QT = 4;                 // 32-query tiles per wave (128 q/wave)
constexpr int BT = 512;               // threads per block (8 waves)
// nn grid = 16 dirs * 8 * 8 = 1024 blocks = exactly 4 per CU

// ws layout (float offsets)
// pts    : [kDirs][kNP] float4 -> 524288 floats @ 0          (2 MB)
// minpart: [kDirs][NCC][kNP] f32 -> 1048576   @ 524288       (4 MB)
// qpart  : [kDirs][NQB][2] f32 -> 256         @ 1572864
// mval   : [kDirs] f32         -> 16          @ 1573120
// dcnt   : [kDirs] u32         -> 16          @ 1573136
// acnt   : u32                 -> 1           @ 1573152
constexpr size_t OFF_MINPART = 524288;
constexpr size_t OFF_QPART = 1572864;
constexpr size_t OFF_MVAL = 1573120;
constexpr size_t OFF_DCNT = 1573136;
constexpr size_t OFF_ACNT = 1573152;

__device__ __forceinline__ unsigned short f2bf(float v) {
  unsigned u = __float_as_uint(v);
  unsigned r = u + 0x7FFFu + ((u >> 16) & 1u);   // RNE
  return (unsigned short)(r >> 16);
}
__device__ __forceinline__ float bf2f(unsigned short b) {
  return __uint_as_float(((unsigned)b) << 16);
}

// Candidate record F (16 bf16 K-slots, K=16 MFMA) with query record G:
//  k : 0    1    2    3    4    5    6    7  | 8    9    10   11   12-15
//  F : Xh   Xl   Xh   Yh   Yl   Yh   Zh   Zl | Zh   Ch   Cl   Cl2  0
//  G : xh   xh   xl   yh   yh   yl   zh   zh | zl   1    1    1    0
// sum_k F*G = X*x + Y*y + Z*z + ct  (drops only lo*lo terms ~2e-4)

__global__ __launch_bounds__(256) void prep_kernel(
    const float* __restrict__ rv, const float* __restrict__ tgt,
    float4* __restrict__ pts, float* __restrict__ mval,
    unsigned* __restrict__ dcnt, unsigned* __restrict__ acnt) {
  int idx = blockIdx.x * 256 + threadIdx.x;   // [0, kPairs*kNP)
  int p = idx >> 13;
  int k = idx & (kNP - 1);
  int h = k >> 7;
  int w = k & 127;

  float r = rv[idx];
  float pitch = (1.0f - (h + 0.5f) * (1.0f / kH)) * (kFovUp - kFovDown) + kFovDown;
  float yaw = -(((w + 0.5f) * (1.0f / kW)) * 2.0f - 1.0f) * kPi;
  float cp = __cosf(pitch), sp = __sinf(pitch);
  float cy = __cosf(yaw), sy = __sinf(yaw);
  float px = r * cp * cy, py = r * cp * sy, pz = r * sp;
  float mo = (r > 0.0f) ? 1.0f : 0.0f;

  const float* tb = tgt + (size_t)p * 4 * kNP;
  float mt = (tb[k] > 0.0f) ? 1.0f : 0.0f;
  float tx = tb[kNP + k], ty = tb[2 * kNP + k], tz = tb[3 * kNP + k];

  float no = px * px + py * py + pz * pz;
  float nt = tx * tx + ty * ty + tz * tz;
  float co = no + kPen * (1.0f - mo);
  float ct = nt + kPen * (1.0f - mt);

  int d0 = 2 * p, d1 = d0 + 1;
  // pts.w < 16384 <=> valid point; equals |p|^2 then. Candidates of dir d
  // are exactly pts[d^1] (dir0 candidates = tgt pts = dir1 queries).
  pts[(size_t)d0 * kNP + k] = make_float4(px, py, pz, co);
  pts[(size_t)d1 * kNP + k] = make_float4(tx, ty, tz, ct);

  if (idx < kDirs) { dcnt[idx] = 0u; mval[idx] = 0.0f; }
  if (idx == kDirs) *acnt = 0u;
  // minpart needs no init: every (d,ch,q) slot is written each launch.
}

__global__ __launch_bounds__(BT) void nn_kernel(
    const float4* __restrict__ pts, float* __restrict__ minpart) {
  // 32 KB candidate records: 32 ctiles of 1 KB = [32 rows x 8 lo][32 rows x 8 hi]
  // laid out so lane l's A-fragment is at byte offset l*16 (linear ds_read_b128).
  // +1 KB slack so the loop's A-prefetch may harmlessly overread one tile.
  __shared__ __align__(16) unsigned short sc[CCH * 16 + 512];

  int bid = blockIdx.x;
  int d = bid >> 6;            // 64 blocks per dir
  int qb = (bid >> 3) & 7;
  int ch = bid & 7;
  int t = threadIdx.x;

  // ---- build candidate records in LDS directly from pts[d^1] ----
  const float4* cand = pts + (size_t)(d ^ 1) * kNP + ch * CCH;
#pragma unroll
  for (int i = 0; i < 2; ++i) {
    int j = t + i * BT;
    float4 P = cand[j];
    float X = -2.0f * P.x, Y = -2.0f * P.y, Z = -2.0f * P.z;
    float ct = P.w;
    unsigned short Xh = f2bf(X), Yh = f2bf(Y), Zh = f2bf(Z);
    unsigned short Xl = f2bf(X - bf2f(Xh));
    unsigned short Yl = f2bf(Y - bf2f(Yh));
    unsigned short Zl = f2bf(Z - bf2f(Zh));
    unsigned short Ch = f2bf(ct);
    float c1 = ct - bf2f(Ch);
    unsigned short Cl = f2bf(c1);
    unsigned short Cl2 = f2bf(c1 - bf2f(Cl));
    // ctile (j>>5): lo-half (k0..7) at slot (j&31), hi-half (k8..15) at +32
    unsigned short* dst = sc + (j >> 5) * 512 + (j & 31) * 8;
    *(ushort8*)dst = (ushort8){Xh, Xl, Xh, Yh, Yl, Yh, Zh, Zl};
    *(ushort8*)(dst + 256) = (ushort8){Zh, Ch, Cl, Cl2, 0, 0, 0, 0};
  }
  __syncthreads();

  int wave = t >> 6, lane = t & 63;
  int col = lane & 31, half = lane >> 5;   // B: col = lane&31 (HW-verified)
  int qbase = d * kNP + qb * 1024 + wave * 128;

  const short one_bf = (short)0x3F80;  // bf16(1.0)
  short8 bq[QT];
  float mn[QT];
#pragma unroll
  for (int qt = 0; qt < QT; ++qt) {
    float4 P = pts[qbase + qt * 32 + col];
    unsigned short xh = f2bf(P.x), yh = f2bf(P.y), zh = f2bf(P.z);
    unsigned short xl = f2bf(P.x - bf2f(xh));
    unsigned short yl = f2bf(P.y - bf2f(yh));
    unsigned short zl = f2bf(P.z - bf2f(zh));
    short8 b;
    if (half == 0)
      b = (short8){(short)xh, (short)xh, (short)xl, (short)yh,
                   (short)yh, (short)yl, (short)zh, (short)zh};
    else
      b = (short8){(short)zl, one_bf, one_bf, one_bf, 0, 0, 0, 0};
    bq[qt] = b;
    mn[qt] = 3.0e38f;
  }

  floatx16 zc = {0.0f, 0.0f, 0.0f, 0.0f, 0.0f, 0.0f, 0.0f, 0.0f,
                 0.0f, 0.0f, 0.0f, 0.0f, 0.0f, 0.0f, 0.0f, 0.0f};

  // A fragment: lane l holds row l&31, K-half l>>5 -> linear offset l*16 B.
  const short8* ap = (const short8*)sc + lane;   // stride 64 short8s per ctile
  short8 a = ap[0];
#pragma unroll 2
  for (int ctile = 0; ctile < CCH / 32; ++ctile) {
    short8 an = ap[(ctile + 1) * 64];   // prefetch next tile (slack covers last)
#pragma unroll
    for (int qt = 0; qt < QT; ++qt) {
      floatx16 dr =
          __builtin_amdgcn_mfma_f32_32x32x16_bf16(a, bq[qt], zc, 0, 0, 0);
      // 16->1 row-min fold, min3-shaped (compiler emits ~8 v_min3)
      float f0 = fminf(fminf(dr[0], dr[1]), dr[2]);
      float f1 = fminf(fminf(dr[3], dr[4]), dr[5]);
      float f2 = fminf(fminf(dr[6], dr[7]), dr[8]);
      float f3 = fminf(fminf(dr[9], dr[10]), dr[11]);
      float f4 = fminf(fminf(dr[12], dr[13]), dr[14]);
      float g0 = fminf(fminf(f0, f1), dr[15]);
      float g1 = fminf(fminf(f2, f3), f4);
      mn[qt] = fminf(fminf(g0, g1), mn[qt]);
    }
    a = an;
  }

  // ---- publish per-chunk partial mins: PLAIN stores, one writer per slot.
  // Cross-kernel visibility to reduce_kernel is handled at the dispatch
  // boundary (same-stream producer->consumer). Then the block simply ends —
  // no syncthreads, no tickets, no winner gathers (the R16/R17 tail).
#pragma unroll
  for (int qt = 0; qt < QT; ++qt) {
    float m = fminf(mn[qt], __shfl_xor(mn[qt], 32));
    if (lane < 32)
      minpart[(size_t)(d * NCC + ch) * kNP + qb * 1024 + wave * 128 +
              qt * 32 + lane] = m;
  }
}

__global__ __launch_bounds__(BT) void reduce_kernel(
    const float4* __restrict__ pts, const float* __restrict__ minpart,
    float* __restrict__ qpart, float* __restrict__ mval,
    unsigned* __restrict__ dcnt, unsigned* __restrict__ acnt,
    float* __restrict__ out) {
  __shared__ unsigned s_ticket;
  __shared__ float sw[8], sm[8];

  int d = blockIdx.x >> 3;     // 8 blocks per dir
  int qb = blockIdx.x & 7;
  int t = threadIdx.x;

  float wsum = 0.0f, msum = 0.0f;
#pragma unroll
  for (int r = 0; r < 1024 / BT; ++r) {     // 2 rows of 512 queries
    int q = qb * 1024 + r * BT + t;         // dir-local query index
    float mv = 3.0e38f;
#pragma unroll
    for (int c = 0; c < NCC; ++c)
      mv = fminf(mv, minpart[(size_t)(d * NCC + c) * kNP + q]);
    float4 P = pts[(size_t)d * kNP + q];
    if (P.w < 16384.0f) {
      wsum += P.w + mv;
      msum += 1.0f;
    }
  }
#pragma unroll
  for (int off = 32; off; off >>= 1) {
    wsum += __shfl_down(wsum, off);
    msum += __shfl_down(msum, off);
  }
  if ((t & 63) == 0) { sw[t >> 6] = wsum; sm[t >> 6] = msum; }
  __syncthreads();
  if (t == 0) {
    float ws_ = 0.0f, ms_ = 0.0f;
#pragma unroll
    for (int w2 = 0; w2 < 8; ++w2) { ws_ += sw[w2]; ms_ += sm[w2]; }
    int g = d * NQB + qb;
    __hip_atomic_store(&qpart[g * 2], ws_, __ATOMIC_RELAXED,
                       __HIP_MEMORY_SCOPE_AGENT);
    __hip_atomic_store(&qpart[g * 2 + 1], ms_, __ATOMIC_RELAXED,
                       __HIP_MEMORY_SCOPE_AGENT);
    // RELEASE publishes the qpart stores (waitcnt only, no L2 flush — the
    // proven R11/R16 pattern). Only 128+16+1 RMWs total in this kernel.
    s_ticket = __hip_atomic_fetch_add(&dcnt[d], 1u, __ATOMIC_ACQ_REL,
                                      __HIP_MEMORY_SCOPE_AGENT);
  }
  __syncthreads();
  if (s_ticket != (unsigned)(NQB - 1)) return;

  // ---- last block of this dir sums the 8 partial pairs (fixed order) ----
  if (t == 0) {
    float W = 0.0f, M = 0.0f;
#pragma unroll
    for (int g = 0; g < NQB; ++g) {
      W += __uint_as_float(__hip_atomic_load(
          (unsigned*)&qpart[(d * NQB + g) * 2], __ATOMIC_RELAXED,
          __HIP_MEMORY_SCOPE_AGENT));
      M += __uint_as_float(__hip_atomic_load(
          (unsigned*)&qpart[(d * NQB + g) * 2 + 1], __ATOMIC_RELAXED,
          __HIP_MEMORY_SCOPE_AGENT));
    }
    __hip_atomic_store(&mval[d], W / fmaxf(M, 1.0f), __ATOMIC_RELAXED,
                       __HIP_MEMORY_SCOPE_AGENT);
    s_ticket = __hip_atomic_fetch_add(acnt, 1u, __ATOMIC_ACQ_REL,
                                      __HIP_MEMORY_SCOPE_AGENT);
  }
  __syncthreads();
  if (s_ticket != (unsigned)(kDirs - 1)) return;
  // ---- very last block combines 16 dir values into the 12 outputs ----
  if (t == 0) {
    float mv[kDirs];
    for (int dd = 0; dd < kDirs; ++dd)
      mv[dd] = __hip_atomic_load(&mval[dd], __ATOMIC_RELAXED,
                                 __HIP_MEMORY_SCOPE_AGENT);
    for (int s = 0; s < kS; ++s) {
      float acc = 0.0f;
      for (int b = 0; b < kB; ++b) {
        int p = b * kS + s;
        float tens = mv[2 * p] + mv[2 * p + 1];
        out[kS + s * kB + b] = tens;
        acc += tens;
      }
      out[s] = acc * (1.0f / kB);
    }
  }
}

extern "C" void kernel_launch(void* const* d_in, const int* in_sizes, int n_in,
                              void* d_out, int out_size, void* d_ws, size_t ws_size,
                              hipStream_t stream) {
  const float* rv = (const float*)d_in[0];
  const float* tgt = (const float*)d_in[1];
  float* ws = (float*)d_ws;
  float4* pts = (float4*)ws;
  float* minpart = ws + OFF_MINPART;
  float* qpart = ws + OFF_QPART;
  float* mval = ws + OFF_MVAL;
  unsigned* dcnt = (unsigned*)(ws + OFF_DCNT);
  unsigned* acnt = (unsigned*)(ws + OFF_ACNT);
  float* out = (float*)d_out;

  hipLaunchKernelGGL(prep_kernel, dim3(kPairs * kNP / 256), dim3(256), 0, stream,
                     rv, tgt, pts, mval, dcnt, acnt);
  hipLaunchKernelGGL(nn_kernel, dim3(kDirs * NQB * NCC), dim3(BT), 0, stream,
                     pts, minpart);
  hipLaunchKernelGGL(reduce_kernel, dim3(kDirs * NQB), dim3(BT), 0, stream,
                     pts, minpart, qpart, mval, dcnt, acnt, out);
}